// Round 8
// baseline (13804.900 us; speedup 1.0000x reference)
//
#include <hip/hip_runtime.h>
#include <cstdint>
#include <cstddef>

#define SS 200
#define NV 100001              // V+1
#define XP_CHUNK 6553600ull    // bytes of xp per lstm-block: 200*1024*32

using short8 = __attribute__((ext_vector_type(8))) short;
using f32x4  = __attribute__((ext_vector_type(4))) float;

__device__ __forceinline__ unsigned short f2bf(float f){
  unsigned int x = __float_as_uint(f);
  x += 0x7fffu + ((x >> 16) & 1u);
  return (unsigned short)(x >> 16);
}
__device__ __forceinline__ float bf2f(unsigned short b){
  return __uint_as_float(((unsigned int)b) << 16);
}
__device__ __forceinline__ float sigm(float x){
  return __builtin_amdgcn_rcpf(1.0f + exp2f(x * -1.44269504f));
}

#define MFB(a,b,c) __builtin_amdgcn_mfma_f32_16x16x32_bf16((a),(b),(c),0,0,0)

// LDS-only barrier (round 7; kept)
#define BAR_LDS() do{                                         \
    __builtin_amdgcn_sched_barrier(0);                        \
    asm volatile("s_waitcnt lgkmcnt(0)" ::: "memory");        \
    __builtin_amdgcn_s_barrier();                             \
    __builtin_amdgcn_sched_barrier(0);                        \
  } while(0)

// ---------------- prep: weight swizzle + token transpose + mask bit-pack ------------
__global__ void prep_kernel(const int* __restrict__ inp,
                            const float* __restrict__ kern,
                            const float* __restrict__ rec,
                            unsigned short* __restrict__ rb,
                            unsigned short* __restrict__ kbf,
                            int* __restrict__ tokT,
                            unsigned long long* __restrict__ maskP){
  int idx = blockIdx.x * 256 + threadIdx.x;
  if (idx < 262144){                    // rec: 256 x 1024, coalesced read
    int k = idx >> 10, col = idx & 1023;
    int gg = col >> 8, w = (col >> 5) & 7, hh = (col >> 4) & 1, l15 = col & 15;
    int kt = k >> 5, hi = (k >> 3) & 3, j = k & 7;
    int lane = l15 + (hi << 4);
    int t = gg * 2 + hh;
    rb[(((w*8 + t)*8 + kt) << 9) + lane*8 + j] = f2bf(rec[idx]);
  }
  if (idx < 65536){                     // kernel: 64 x 1024
    int k = idx >> 10, col = idx & 1023;
    int zt = col >> 4, l15 = col & 15;
    int kt = k >> 5, hi = (k >> 3) & 3, j = k & 7;
    kbf[(((zt << 1) + kt) << 9) + (l15 + (hi << 4))*8 + j] = f2bf(kern[idx]);
  }
  if (idx < 204800){                    // token transpose
    int s = idx >> 10, b = idx & 1023;
    tokT[idx] = inp[b * SS + s];
  }
  if (idx < 4096){                      // mask bit-pack: b = idx>>2, seg = idx&3
    int b = idx >> 2, seg = idx & 3;
    unsigned long long bits = 0ull;
    int base = b * SS + seg * 64;
    int n = (seg < 3) ? 64 : (SS - 192);
    for (int i = 0; i < n; ++i)
      if (inp[base + i] != 0) bits |= (1ull << i);
    maskP[idx] = bits;
  }
}

// ---------------- xproj: z_x[b][s][:] = emb[tok] @ kernel + bias --------------------
__global__ void __launch_bounds__(256)
xproj_kernel(const float* __restrict__ emb,
             const float* __restrict__ bias,
             const unsigned short* __restrict__ kbf,
             const int* __restrict__ tokT,
             float* __restrict__ dout,
             char* __restrict__ wsxp){
  __shared__ char ldsB[2048];
  const int bid = blockIdx.x;
  const int blk = bid / 200;
  const int s   = bid - blk * 200;
  const int b0  = blk << 4;
  const int tid = threadIdx.x;
  const int lane = tid & 63;
  const int w4  = tid >> 6;
  const int l15 = lane & 15;
  const int l4  = lane >> 4;

  {
    int row = tid >> 4, e0 = (tid & 15) << 2;
    int tok = tokT[s*1024 + b0 + row];
    float4 xv = *(const float4*)(emb + (size_t)tok * 64 + e0);
    float vq[4] = {xv.x, xv.y, xv.z, xv.w};
    #pragma unroll
    for (int q = 0; q < 4; ++q){
      int e = e0 + q, kt = e >> 5, hi = (e & 31) >> 3, j = e & 7;
      *(unsigned short*)(ldsB + kt*1024 + (row + (hi << 4))*16 + (j << 1)) = f2bf(vq[q]);
    }
  }
  __syncthreads();
  short8 xb0 = *(const short8*)(ldsB + (lane << 4));
  short8 xb1 = *(const short8*)(ldsB + 1024 + (lane << 4));

  char* xpb = (blk < 62) ? ((char*)dout + (size_t)blk * XP_CHUNK)
                         : (wsxp + (size_t)(blk - 62) * XP_CHUNK);
  xpb += (size_t)s * 32768;

  #pragma unroll 4
  for (int i = 0; i < 16; ++i){
    int zt = (w4 << 4) + i;
    f32x4 acc = *(const f32x4*)(bias + (zt << 4) + (l4 << 2));
    short8 a0 = *(const short8*)(kbf + (((zt << 1) + 0) << 9) + (lane << 3));
    short8 a1 = *(const short8*)(kbf + (((zt << 1) + 1) << 9) + (lane << 3));
    acc = MFB(a0, xb0, acc);
    acc = MFB(a1, xb1, acc);
    unsigned int p0, p1;
    asm("v_cvt_pk_bf16_f32 %0, %1, %2" : "=v"(p0) : "v"(acc[0]), "v"(acc[1]));
    asm("v_cvt_pk_bf16_f32 %0, %1, %2" : "=v"(p1) : "v"(acc[2]), "v"(acc[3]));
    int gg = zt >> 4, w = (zt >> 1) & 7, hh = zt & 1;
    int tid_l = ((w << 1) + hh)*64 + (l4 << 4) + l15;
    *(uint2*)(xpb + tid_l*32 + (gg << 3)) = make_uint2(p0, p1);
  }
}

// ---------------- ABLATION PROBE: step skeleton only, REPS x 200 steps --------------
// Identical 16-wave step structure (xp prefetch, gates, masked update, ds_write,
// BAR_LDS) with NO MFMA / NO LDS reads / NO weight streams. Measures the
// irreducible skeleton cost per step. Writes hbuf (overwritten by real lstm).
template<int REPS>
__global__ void __attribute__((amdgpu_flat_work_group_size(1024, 1024),
                               amdgpu_waves_per_eu(4, 4)))
lstm_skel(const unsigned long long* __restrict__ maskP,
          const float* __restrict__ dout_xp,
          const char* __restrict__ wsxp,
          float* __restrict__ hout){
  extern __shared__ char smem[];
  char* const hA = smem;
  char* const hB = smem + 8192;
  const int tid  = threadIdx.x;
  const int lane = tid & 63;
  const int wv   = tid >> 6;
  const int w    = wv >> 1;
  const int hh   = wv & 1;
  const int l15  = lane & 15;
  const int l4   = lane >> 4;
  const int blk  = blockIdx.x;
  const int b0   = blk << 4;

  *(unsigned long long*)(hA + tid*8) = 0ull;
  *(unsigned long long*)(hB + tid*8) = 0ull;

  const char* xp_base = ((blk < 62) ? ((const char*)dout_xp + (size_t)blk * XP_CHUNK)
                                    : (wsxp + (size_t)(blk - 62) * XP_CHUNK)) + tid*32;
  const unsigned long long* maskB = maskP + (size_t)(b0 + l15) * 4;

  float c[4] = {0.f, 0.f, 0.f, 0.f};
  unsigned long long pkPrev = 0ull;
  const int lane_a = l15 + ((hh*2 + (l4 >> 1)) << 4);
  const int wb_off = (w << 10) + lane_a*16 + ((l4 & 1) << 3);

  __syncthreads();

  #pragma unroll 1
  for (int rep = 0; rep < REPS; ++rep){
    uint4 xca = *(const uint4*)(xp_base);
    uint4 xcb = *(const uint4*)(xp_base + 16);
    const char* xp_ptr = xp_base + 32768;
    int s = 0;
    #pragma unroll 1
    for (int seg = 0; seg < 4; ++seg){
      unsigned long long cur = maskB[seg];
      const int nn = (seg < 3) ? 64 : (SS - 192);
      #pragma unroll 1
      for (int i = 0; i < nn; ++i, ++s){
        char* wr2 = (s & 1) ? hA : hB;

        uint4 xna = *(const uint4*)(xp_ptr);
        uint4 xnb = *(const uint4*)(xp_ptr + 16);
        if (s < SS - 2) xp_ptr += 32768;

        f32x4 acc[4];
        #pragma unroll
        for (int gg = 0; gg < 4; ++gg){
          unsigned int u0 = (gg==0) ? xca.x : (gg==1) ? xca.z : (gg==2) ? xcb.x : xcb.z;
          unsigned int u1 = (gg==0) ? xca.y : (gg==1) ? xca.w : (gg==2) ? xcb.y : xcb.w;
          acc[gg] = f32x4{ __uint_as_float(u0 << 16),
                           __uint_as_float(u0 & 0xffff0000u),
                           __uint_as_float(u1 << 16),
                           __uint_as_float(u1 & 0xffff0000u) };
        }

        int tkb = (int)(cur & 1ull);
        cur >>= 1;
        float hv0, hv1, hv2, hv3;
        #pragma unroll
        for (int r = 0; r < 4; ++r){
          float si = sigm(acc[0][r]);
          float sf = sigm(acc[1][r]);
          float sg = sigm(acc[2][r]);
          float so = sigm(acc[3][r]);
          float cn = sf * c[r] + si * sg;
          float hv = so * sigm(cn);
          if (tkb) c[r] = cn;
          if (r == 0) hv0 = hv; else if (r == 1) hv1 = hv;
          else if (r == 2) hv2 = hv; else hv3 = hv;
        }
        unsigned int pLo, pHi;
        asm("v_cvt_pk_bf16_f32 %0, %1, %2" : "=v"(pLo) : "v"(hv0), "v"(hv1));
        asm("v_cvt_pk_bf16_f32 %0, %1, %2" : "=v"(pHi) : "v"(hv2), "v"(hv3));
        unsigned long long pkNew = (((unsigned long long)pHi) << 32) | pLo;
        unsigned long long pk = tkb ? pkNew : pkPrev;
        pkPrev = pk;
        *(unsigned long long*)(wr2 + wb_off) = pk;

        xca = xna; xcb = xnb;

        BAR_LDS();
      }
    }
  }

  // fold LDS state back in so the per-step ds_writes are provably live
  unsigned long long chk = *(const unsigned long long*)(hA + wb_off)
                         ^ *(const unsigned long long*)(hB + wb_off)
                         ^ pkPrev;
  {
    int u0 = w*32 + hh*16 + (l4 << 2);
    *(float4*)(hout + (b0 + l15)*256 + u0) =
      make_float4(bf2f((unsigned short)( chk        & 0xffff)),
                  bf2f((unsigned short)((chk >> 16) & 0xffff)),
                  bf2f((unsigned short)((chk >> 32) & 0xffff)),
                  bf2f((unsigned short)((chk >> 48) & 0xffff)));
  }
}

// ---------------- LSTM (real, unchanged from round 7) -------------------------------
__global__ void __attribute__((amdgpu_flat_work_group_size(1024, 1024),
                               amdgpu_waves_per_eu(4, 4)))
lstm_kernel(const unsigned short* __restrict__ rb,
            const unsigned long long* __restrict__ maskP,
            const float* __restrict__ dout_xp,
            const char* __restrict__ wsxp,
            float* __restrict__ hout){
  extern __shared__ char smem[];
  char* const hA   = smem;              // 8192
  char* const hB   = smem + 8192;       // 8192
  char* const rBl  = smem + 16384;      // 65536 (rec kt4)
  char* const rBl2 = smem + 81920;      // 65536 (rec kt5)
  const int tid  = threadIdx.x;
  const int lane = tid & 63;
  const int wv   = tid >> 6;
  const int w    = wv >> 1;
  const int hh   = wv & 1;
  const int l15  = lane & 15;
  const int l4   = lane >> 4;
  const int blk  = blockIdx.x;
  const int b0   = blk << 4;

  #define RBF(gg,kt) (*(const short8*)(rb + (((w*8 + ((gg)*2+hh))*8 + (kt)) << 9) + (lane<<3)))

  {
    int fid = tid >> 4, p = tid & 15;
    const int4* s4 = (const int4*)(rb + ((fid*8 + 4) << 9) + p*32);
    const int4* s5 = (const int4*)(rb + ((fid*8 + 5) << 9) + p*32);
    int4* d4 = (int4*)(rBl  + fid*1024 + p*64);
    int4* d5 = (int4*)(rBl2 + fid*1024 + p*64);
    #pragma unroll
    for (int q = 0; q < 4; ++q){ d4[q] = s4[q]; d5[q] = s5[q]; }
  }
  *(unsigned long long*)(hA + tid*8) = 0ull;   // h0 = 0

  short8 Wr[3][4];
  #pragma unroll
  for (int kt = 0; kt < 3; ++kt)
    #pragma unroll
    for (int gg = 0; gg < 4; ++gg) Wr[kt][gg] = RBF(gg, kt);

  const char* xp_base = ((blk < 62) ? ((const char*)dout_xp + (size_t)blk * XP_CHUNK)
                                    : (wsxp + (size_t)(blk - 62) * XP_CHUNK)) + tid*32;
  const unsigned long long* maskB = maskP + (size_t)(b0 + l15) * 4;

  uint4 xca = *(const uint4*)(xp_base);
  uint4 xcb = *(const uint4*)(xp_base + 16);
  const char* xp_ptr = xp_base + 32768;   // -> step 1
  short8 S[4];
  #pragma unroll
  for (int gg = 0; gg < 4; ++gg) S[gg] = RBF(gg, 3);

  float c[4] = {0.f, 0.f, 0.f, 0.f};
  unsigned long long pkPrev = 0ull;
  const int lane_a = l15 + ((hh*2 + (l4 >> 1)) << 4);
  const int wb_off = (w << 10) + lane_a*16 + ((l4 & 1) << 3);

  __syncthreads();

  int s = 0;
  #pragma unroll 1
  for (int seg = 0; seg < 4; ++seg){
    unsigned long long cur = maskB[seg];
    const int nn = (seg < 3) ? 64 : (SS - 192);
    #pragma unroll 1
    for (int i = 0; i < nn; ++i, ++s){
      const char* rd  = (s & 1) ? hB : hA;
      char*       wr2 = (s & 1) ? hA : hB;

      uint4 xna = *(const uint4*)(xp_ptr);
      uint4 xnb = *(const uint4*)(xp_ptr + 16);
      if (s < SS - 2) xp_ptr += 32768;

      f32x4 acc[4];
      #pragma unroll
      for (int gg = 0; gg < 4; ++gg){
        unsigned int u0 = (gg==0) ? xca.x : (gg==1) ? xca.z : (gg==2) ? xcb.x : xcb.z;
        unsigned int u1 = (gg==0) ? xca.y : (gg==1) ? xca.w : (gg==2) ? xcb.y : xcb.w;
        acc[gg] = f32x4{ __uint_as_float(u0 << 16),
                         __uint_as_float(u0 & 0xffff0000u),
                         __uint_as_float(u1 << 16),
                         __uint_as_float(u1 & 0xffff0000u) };
      }

      #pragma unroll
      for (int kt = 0; kt < 3; ++kt){
        short8 h = *(const short8*)(rd + kt*1024 + (lane << 4));
        #pragma unroll
        for (int gg = 0; gg < 4; ++gg) acc[gg] = MFB(Wr[kt][gg], h, acc[gg]);
      }
      {
        short8 h3 = *(const short8*)(rd + 3*1024 + (lane << 4));
        #pragma unroll
        for (int gg = 0; gg < 4; ++gg) acc[gg] = MFB(S[gg], h3, acc[gg]);
      }
      #pragma unroll
      for (int gg = 0; gg < 4; ++gg) S[gg] = RBF(gg, 6);   // issue kt6

      {
        short8 h4 = *(const short8*)(rd + 4*1024 + (lane << 4));
        #pragma unroll
        for (int gg = 0; gg < 4; ++gg){
          short8 bw = *(const short8*)(rBl + (w*8 + gg*2+hh)*1024 + (lane << 4));
          acc[gg] = MFB(bw, h4, acc[gg]);
        }
      }
      {
        short8 h6 = *(const short8*)(rd + 6*1024 + (lane << 4));
        #pragma unroll
        for (int gg = 0; gg < 4; ++gg) acc[gg] = MFB(S[gg], h6, acc[gg]);
      }
      #pragma unroll
      for (int gg = 0; gg < 4; ++gg) S[gg] = RBF(gg, 7);   // issue kt7

      {
        short8 h5 = *(const short8*)(rd + 5*1024 + (lane << 4));
        #pragma unroll
        for (int gg = 0; gg < 4; ++gg){
          short8 bw = *(const short8*)(rBl2 + (w*8 + gg*2+hh)*1024 + (lane << 4));
          acc[gg] = MFB(bw, h5, acc[gg]);
        }
      }
      {
        short8 h7 = *(const short8*)(rd + 7*1024 + (lane << 4));
        #pragma unroll
        for (int gg = 0; gg < 4; ++gg) acc[gg] = MFB(S[gg], h7, acc[gg]);
      }
      #pragma unroll
      for (int gg = 0; gg < 4; ++gg) S[gg] = RBF(gg, 3);   // issue kt3 for NEXT step

      int tkb = (int)(cur & 1ull);
      cur >>= 1;
      float hv0, hv1, hv2, hv3;
      #pragma unroll
      for (int r = 0; r < 4; ++r){
        float si = sigm(acc[0][r]);
        float sf = sigm(acc[1][r]);
        float sg = sigm(acc[2][r]);
        float so = sigm(acc[3][r]);
        float cn = sf * c[r] + si * sg;
        float hv = so * sigm(cn);
        if (tkb) c[r] = cn;
        if (r == 0) hv0 = hv; else if (r == 1) hv1 = hv;
        else if (r == 2) hv2 = hv; else hv3 = hv;
      }
      unsigned int pLo, pHi;
      asm("v_cvt_pk_bf16_f32 %0, %1, %2" : "=v"(pLo) : "v"(hv0), "v"(hv1));
      asm("v_cvt_pk_bf16_f32 %0, %1, %2" : "=v"(pHi) : "v"(hv2), "v"(hv3));
      unsigned long long pkNew = (((unsigned long long)pHi) << 32) | pLo;
      unsigned long long pk = tkb ? pkNew : pkPrev;
      pkPrev = pk;
      *(unsigned long long*)(wr2 + wb_off) = pk;

      xca = xna; xcb = xnb;

      BAR_LDS();
    }
  }

  {
    int u0 = w*32 + hh*16 + (l4 << 2);
    *(float4*)(hout + (b0 + l15)*256 + u0) =
      make_float4(bf2f((unsigned short)( pkPrev        & 0xffff)),
                  bf2f((unsigned short)((pkPrev >> 16) & 0xffff)),
                  bf2f((unsigned short)((pkPrev >> 32) & 0xffff)),
                  bf2f((unsigned short)((pkPrev >> 48) & 0xffff)));
  }
  #undef RBF
}

// ---------------- dense: out = h @ dense_w + dense_b  (1024x64, K=256) --------------
__global__ void dense_kernel(const float* __restrict__ h,
                             const float* __restrict__ dw,
                             const float* __restrict__ db,
                             float* __restrict__ outv){
  int tid = threadIdx.x;
  int e = tid & 63;
  int b = blockIdx.x * 4 + (tid >> 6);
  const float* hb = h + b * 256;
  float a = db[e];
  #pragma unroll 8
  for (int u = 0; u < 256; ++u) a = fmaf(hb[u], dw[u*64 + e], a);
  outv[b*64 + e] = a;
}

// ---------------- logits: dst = out @ emb.T  (1024 x 100001, K=64, fp32) ------------
__global__ void __launch_bounds__(256)
logits_kernel(const float* __restrict__ outv,
              const float* __restrict__ emb,
              float* __restrict__ dst){
  int v = blockIdx.x * 256 + threadIdx.x;
  const bool valid = (v < NV);
  const int vs = valid ? v : 0;
  const int bb = blockIdx.y * 256;
  float er[64];
  #pragma unroll
  for (int q = 0; q < 16; ++q){
    float4 tq = *(const float4*)(emb + (size_t)vs * 64 + q*4);
    er[q*4+0] = tq.x; er[q*4+1] = tq.y; er[q*4+2] = tq.z; er[q*4+3] = tq.w;
  }
  for (int b = bb; b < bb + 256; ++b){
    const float* ob = outv + b*64;   // wave-uniform -> scalar loads
    float a0 = 0.f, a1 = 0.f;
    #pragma unroll
    for (int e = 0; e < 64; e += 2){
      a0 = fmaf(ob[e],   er[e],   a0);
      a1 = fmaf(ob[e+1], er[e+1], a1);
    }
    if (valid) dst[(size_t)b * NV + v] = a0 + a1;
  }
}

extern "C" void kernel_launch(void* const* d_in, const int* in_sizes, int n_in,
                              void* d_out, int out_size, void* d_ws, size_t ws_size,
                              hipStream_t stream){
  const int*   inp  = (const int*)  d_in[0];
  const float* emb  = (const float*)d_in[1];
  const float* kern = (const float*)d_in[2];
  const float* rec  = (const float*)d_in[3];
  const float* bias = (const float*)d_in[4];
  const float* dw   = (const float*)d_in[5];
  const float* db   = (const float*)d_in[6];
  float* dst = (float*)d_out;
  char* ws = (char*)d_ws;

  unsigned short*     rb    = (unsigned short*)    (ws);            // 524288 B
  unsigned short*     kbf   = (unsigned short*)    (ws + 524288);   // 131072 B
  int*                tokT  = (int*)               (ws + 655360);   // 819200 B
  unsigned long long* maskP = (unsigned long long*)(ws + 1474560);  // 32768 B
  float*              hbuf  = (float*)             (ws + 1507328);  // 1048576 B
  float*              obuf  = (float*)             (ws + 2555904);  // 262144 B
  char*               wsxp  = (char*)              (ws + 2818048);  // 13107200 B

  const int SMEM_BYTES = 147456;
  hipFuncSetAttribute((const void*)lstm_kernel,
                      hipFuncAttributeMaxDynamicSharedMemorySize, SMEM_BYTES);
  hipFuncSetAttribute(reinterpret_cast<const void*>(&lstm_skel<40>),
                      hipFuncAttributeMaxDynamicSharedMemorySize, SMEM_BYTES);

  prep_kernel  <<<1024, 256, 0, stream>>>(inp, kern, rec, rb, kbf, tokT, maskP);
  xproj_kernel <<<12800, 256, 0, stream>>>(emb, bias, kbf, tokT, dst, wsxp);
  // ABLATION PROBE: skeleton-only step, 40 x 200 steps; hbuf overwritten by real lstm
  lstm_skel<40><<<64, 1024, SMEM_BYTES, stream>>>(maskP, dst, wsxp, hbuf);
  lstm_kernel  <<<64, 1024, SMEM_BYTES, stream>>>(rb, maskP, dst, wsxp, hbuf);
  dense_kernel <<<256, 256, 0, stream>>>(hbuf, dw, db, obuf);
  logits_kernel<<<dim3(391, 4), 256, 0, stream>>>(obuf, emb, dst);
  (void)in_sizes; (void)n_in; (void)out_size; (void)ws_size;
}

// Round 9
// 861.395 us; speedup vs baseline: 16.0262x; 16.0262x over previous
//
#include <hip/hip_runtime.h>
#include <cstdint>
#include <cstddef>

#define SS 200
#define NV 100001   // V+1

using int4v = __attribute__((ext_vector_type(4))) int;
using f32x4 = __attribute__((ext_vector_type(4))) float;

__device__ __forceinline__ float sigm(float x){
  return __builtin_amdgcn_rcpf(1.0f + exp2f(x * -1.44269504f));
}
__device__ __forceinline__ int q8(float v, float inv_s){
  float q = rintf(v * inv_s);
  q = fminf(127.f, fmaxf(-127.f, q));
  return (int)q;
}

#define MFI(a,b,c) __builtin_amdgcn_mfma_i32_16x16x64_i8((a),(b),(c),0,0,0)

// LDS-only barrier: orders LDS h/x traffic; leaves global loads in flight.
#define BAR_LDS() do{                                         \
    __builtin_amdgcn_sched_barrier(0);                        \
    asm volatile("s_waitcnt lgkmcnt(0)" ::: "memory");        \
    __builtin_amdgcn_s_barrier();                             \
    __builtin_amdgcn_sched_barrier(0);                        \
  } while(0)

// ---------------- scale: absmax of rec and kernel -> sc[0], sc[1] (float bits) ------
__global__ void scale_kernel(const float* __restrict__ rec,
                             const float* __restrict__ kern,
                             int* __restrict__ sc){
  __shared__ float red[256];
  int tid = threadIdx.x;
  float mr = 0.f, mk = 0.f;
  for (int i = blockIdx.x*256 + tid; i < 262144; i += 256*64) mr = fmaxf(mr, fabsf(rec[i]));
  for (int i = blockIdx.x*256 + tid; i <  65536; i += 256*64) mk = fmaxf(mk, fabsf(kern[i]));
  red[tid] = mr; __syncthreads();
  for (int o = 128; o > 0; o >>= 1){ if (tid < o) red[tid] = fmaxf(red[tid], red[tid+o]); __syncthreads(); }
  if (tid == 0) atomicMax(sc + 0, __float_as_int(red[0]));
  __syncthreads();
  red[tid] = mk; __syncthreads();
  for (int o = 128; o > 0; o >>= 1){ if (tid < o) red[tid] = fmaxf(red[tid], red[tid+o]); __syncthreads(); }
  if (tid == 0) atomicMax(sc + 1, __float_as_int(red[0]));
}

// ---------------- prep: i8 quantized weight frags + per-block tokens + mask bits ----
// rq  : rec i8 A-frags [tile(64)][ktt(4)][lane(64)][j(16)]   tile = w*8+gg*2+hh
// kq  : kern i8 A-frags [tile(64)][lane(64)][j(16)]          (K=64 -> 1 ktt)
// tokB: tokens per lstm-block [blk(64)][s(200)][r(16)]
// maskP: mask bits, 4 x u64 per batch row
__global__ void prep_kernel(const int* __restrict__ inp,
                            const float* __restrict__ kern,
                            const float* __restrict__ rec,
                            const int* __restrict__ sc,
                            char* __restrict__ rq,
                            char* __restrict__ kq,
                            int* __restrict__ tokB,
                            unsigned long long* __restrict__ maskP){
  int idx = blockIdx.x * 256 + threadIdx.x;
  float maxr = __int_as_float(sc[0]);
  float maxk = __int_as_float(sc[1]);
  if (idx < 262144){                    // rec: 256 x 1024, coalesced read
    int k = idx >> 10, col = idx & 1023;
    int gg = col >> 8, w = (col >> 5) & 7, hh = (col >> 4) & 1, l15 = col & 15;
    int tile = w*8 + gg*2 + hh;
    int ktt = k >> 6, hi = (k >> 4) & 3, j = k & 15;
    int lane = l15 + (hi << 4);
    rq[((tile*4 + ktt) << 10) + lane*16 + j] = (char)q8(rec[idx], 127.f/maxr);
  }
  if (idx < 65536){                     // kernel: 64 x 1024
    int k = idx >> 10, col = idx & 1023;
    int gg = col >> 8, w = (col >> 5) & 7, hh = (col >> 4) & 1, l15 = col & 15;
    int tile = w*8 + gg*2 + hh;
    int hi = (k >> 4) & 3, j = k & 15;
    int lane = l15 + (hi << 4);
    kq[(tile << 10) + lane*16 + j] = (char)q8(kern[idx], 127.f/maxk);
  }
  if (idx < 204800){                    // tokens: [blk][s][r]
    int s = idx >> 10, b = idx & 1023;
    int blk = b >> 4, r = b & 15;
    tokB[(blk*SS + s)*16 + r] = inp[b*SS + s];
  }
  if (idx < 4096){                      // mask bit-pack: b = idx>>2, seg = idx&3
    int b = idx >> 2, seg = idx & 3;
    unsigned long long bits = 0ull;
    int base = b * SS + seg * 64;
    int n = (seg < 3) ? 64 : (SS - 192);
    for (int i = 0; i < n; ++i)
      if (inp[base + i] != 0) bits |= (1ull << i);
    maskP[idx] = bits;
  }
}

// ---------------- LSTM: 64 blocks x 1024 thr (16 waves); all-i8, all-resident -------
// Wave (w,hh) owns gate-tiles gg=0..3 (u-cols w*32+hh*16..+15). Thread: batch l15,
// u = l4*4+r. Rec weights: 16 i8 frags VGPR-resident (64 VGPR). Kern weights: LDS
// (64 KB). Per step global traffic = one emb row per wave (256 B, L3) — the xp
// stream (2 MB/step, the round-8 skeleton's 667 GB/s bottleneck) is GONE.
// Shared-acc trick: s_x = s_rec*s_h/s_kern so rec+x MFMAs share one i32 acc.
// LDS: h 2x4352 (stride 272: 2-way banks) | x 2x1280 (stride 80) | Wx 64K |
//      tok 12.8K | bias 4K = 93696 B
__global__ void __attribute__((amdgpu_flat_work_group_size(1024, 1024),
                               amdgpu_waves_per_eu(4, 4)))
lstm_kernel(const float* __restrict__ emb,
            const float* __restrict__ bias,
            const char* __restrict__ rq,
            const char* __restrict__ kq,
            const int* __restrict__ tokB,
            const unsigned long long* __restrict__ maskP,
            const int* __restrict__ sc,
            float* __restrict__ hout){
  extern __shared__ char smem[];
  char*  const hbuf0 = smem;                    // 2 x 4352
  char*  const xbuf0 = smem + 8704;             // 2 x 1280
  char*  const WxL   = smem + 11264;            // 65536
  int*   const tokL  = (int*)(smem + 76800);    // 12800
  float* const biasL = (float*)(smem + 89600);  // 4096
  const int tid  = threadIdx.x;
  const int lane = tid & 63;
  const int wv   = tid >> 6;       // 0..15
  const int w    = wv >> 1;
  const int hh   = wv & 1;
  const int l15  = lane & 15;
  const int l4   = lane >> 4;
  const int blk  = blockIdx.x;
  const int b0   = blk << 4;

  const float maxr = __int_as_float(sc[0]);
  const float maxk = __int_as_float(sc[1]);
  const float S      = maxr * (1.f/16129.f);    // s_rec * s_h = maxr/127^2
  const float inv_sx = 127.f * maxk / maxr;     // 1/s_x

  // ---- prologue staging ----
  {  // Wx: 64 KB linear
    const int4* src = (const int4*)(kq + tid*64);
    int4* dst = (int4*)(WxL + tid*64);
    #pragma unroll
    for (int q = 0; q < 4; ++q) dst[q] = src[q];
  }
  #pragma unroll
  for (int q = 0; q < 4; ++q){  // tokens: 3200 ints
    int ii = tid + q*1024;
    if (ii < 3200) tokL[ii] = tokB[blk*3200 + ii];
  }
  biasL[tid] = bias[tid];
  {  // zero h buffer 0 (4352 B)
    for (int off = tid*8; off < 4352; off += 8192)
      *(unsigned long long*)(hbuf0 + off) = 0ull;
  }
  // resident rec frags: 16 x int4v = 64 VGPR
  int4v Wr[4][4];
  #pragma unroll
  for (int ktt = 0; ktt < 4; ++ktt)
    #pragma unroll
    for (int gg = 0; gg < 4; ++gg)
      Wr[ktt][gg] = *(const int4v*)(rq + ((((w*8 + gg*2+hh)*4 + ktt)) << 10) + (lane << 4));
  // x(0): wave wv stages batch row wv
  {
    int tok0 = tokB[blk*3200 + wv];
    float xv0 = emb[(size_t)tok0 * 64 + lane];
    *(char*)(xbuf0 + wv*80 + lane) = (char)q8(xv0, inv_sx);
  }

  const unsigned long long* maskB = maskP + (size_t)(b0 + l15) * 4;
  float c[4]  = {0.f, 0.f, 0.f, 0.f};
  float hr[4] = {0.f, 0.f, 0.f, 0.f};
  const int h_rd  = l15*272 + l4*16;                         // + ktt*64
  const int h_wr  = l15*272 + (w<<5) + (hh<<4) + (l4<<2);
  const int x_rd  = l15*80 + l4*16;
  const int x_wr  = wv*80 + lane;
  const int b_rd  = w*32 + hh*16 + (l4<<2);                  // float idx, + gg*256

  __syncthreads();

  int s = 0;
  #pragma unroll 1
  for (int seg = 0; seg < 4; ++seg){
    unsigned long long cur = maskB[seg];
    const int nn = (seg < 3) ? 64 : (SS - 192);
    #pragma unroll 1
    for (int i = 0; i < nn; ++i, ++s){
      const char* hc = hbuf0 + ((s & 1) ? 4352 : 0);
      char*       hn = hbuf0 + ((s & 1) ? 0 : 4352);
      const char* xc = xbuf0 + ((s & 1) ? 1280 : 0);
      char*       xn = xbuf0 + ((s & 1) ? 0 : 1280);

      // issue next emb row early (wave-uniform token -> coalesced 256 B, ~L3)
      float xvN = 0.f;
      if (s + 1 < SS){
        int tokn = tokL[(s+1)*16 + wv];
        xvN = emb[(size_t)tokn * 64 + lane];
      }

      // MFMA: 4 rec ktt + 1 x per gate, shared i32 acc
      int4v acc[4];
      #pragma unroll
      for (int gg = 0; gg < 4; ++gg) acc[gg] = int4v{0,0,0,0};
      {
        int4v xf = *(const int4v*)(xc + x_rd);
        #pragma unroll
        for (int gg = 0; gg < 4; ++gg){
          int4v wx = *(const int4v*)(WxL + ((w*8 + gg*2+hh) << 10) + (lane << 4));
          acc[gg] = MFI(wx, xf, acc[gg]);
        }
      }
      #pragma unroll
      for (int ktt = 0; ktt < 4; ++ktt){
        int4v hf = *(const int4v*)(hc + h_rd + ktt*64);
        #pragma unroll
        for (int gg = 0; gg < 4; ++gg) acc[gg] = MFI(Wr[ktt][gg], hf, acc[gg]);
      }

      // gates: z = bias + S*acc ; all-sigmoid LSTM; masked rows keep c,h
      f32x4 bv0 = *(const f32x4*)(biasL + b_rd);
      f32x4 bv1 = *(const f32x4*)(biasL + 256 + b_rd);
      f32x4 bv2 = *(const f32x4*)(biasL + 512 + b_rd);
      f32x4 bv3 = *(const f32x4*)(biasL + 768 + b_rd);
      int tkb = (int)(cur & 1ull);
      cur >>= 1;
      #pragma unroll
      for (int r = 0; r < 4; ++r){
        float zi = fmaf(S, (float)acc[0][r], bv0[r]);
        float zf = fmaf(S, (float)acc[1][r], bv1[r]);
        float zg = fmaf(S, (float)acc[2][r], bv2[r]);
        float zo = fmaf(S, (float)acc[3][r], bv3[r]);
        float si = sigm(zi), sf = sigm(zf), sg = sigm(zg), so = sigm(zo);
        float cn = sf * c[r] + si * sg;
        float hv = so * sigm(cn);
        if (tkb){ c[r] = cn; hr[r] = hv; }
      }
      // quantize h (kept values requantize identically) and write i8x4
      unsigned int pk = 0u;
      #pragma unroll
      for (int r = 0; r < 4; ++r)
        pk |= ((unsigned int)(int)rintf(hr[r] * 127.f)) << (8*r);
      *(unsigned int*)(hn + h_wr) = pk;

      // stage next x (i8)
      if (s + 1 < SS)
        *(char*)(xn + x_wr) = (char)q8(xvN, inv_sx);

      BAR_LDS();   // LDS-only barrier
    }
  }

  // final h (fp32)
  *(float4*)(hout + (b0 + l15)*256 + w*32 + hh*16 + (l4<<2)) =
      make_float4(hr[0], hr[1], hr[2], hr[3]);
}

// ---------------- dense: out = h @ dense_w + dense_b  (1024x64, K=256) --------------
__global__ void dense_kernel(const float* __restrict__ h,
                             const float* __restrict__ dw,
                             const float* __restrict__ db,
                             float* __restrict__ outv){
  int tid = threadIdx.x;
  int e = tid & 63;
  int b = blockIdx.x * 4 + (tid >> 6);
  const float* hb = h + b * 256;
  float a = db[e];
  #pragma unroll 8
  for (int u = 0; u < 256; ++u) a = fmaf(hb[u], dw[u*64 + e], a);
  outv[b*64 + e] = a;
}

// ---------------- logits: dst = out @ emb.T  (1024 x 100001, K=64, fp32) ------------
__global__ void __launch_bounds__(256)
logits_kernel(const float* __restrict__ outv,
              const float* __restrict__ emb,
              float* __restrict__ dst){
  int v = blockIdx.x * 256 + threadIdx.x;
  const bool valid = (v < NV);
  const int vs = valid ? v : 0;
  const int bb = blockIdx.y * 256;
  float er[64];
  #pragma unroll
  for (int q = 0; q < 16; ++q){
    float4 tq = *(const float4*)(emb + (size_t)vs * 64 + q*4);
    er[q*4+0] = tq.x; er[q*4+1] = tq.y; er[q*4+2] = tq.z; er[q*4+3] = tq.w;
  }
  for (int b = bb; b < bb + 256; ++b){
    const float* ob = outv + b*64;   // wave-uniform -> scalar loads
    float a0 = 0.f, a1 = 0.f;
    #pragma unroll
    for (int e = 0; e < 64; e += 2){
      a0 = fmaf(ob[e],   er[e],   a0);
      a1 = fmaf(ob[e+1], er[e+1], a1);
    }
    if (valid) dst[(size_t)b * NV + v] = a0 + a1;
  }
}

extern "C" void kernel_launch(void* const* d_in, const int* in_sizes, int n_in,
                              void* d_out, int out_size, void* d_ws, size_t ws_size,
                              hipStream_t stream){
  const int*   inp  = (const int*)  d_in[0];
  const float* emb  = (const float*)d_in[1];
  const float* kern = (const float*)d_in[2];
  const float* rec  = (const float*)d_in[3];
  const float* bias = (const float*)d_in[4];
  const float* dw   = (const float*)d_in[5];
  const float* db   = (const float*)d_in[6];
  float* dst = (float*)d_out;
  char* ws = (char*)d_ws;

  int*                sc    = (int*)               (ws);            // 8 B (+pad)
  char*               rq    = (char*)              (ws + 4096);     // 262144 B
  char*               kq    = (char*)              (ws + 266240);   // 65536 B
  int*                tokB  = (int*)               (ws + 331776);   // 819200 B
  unsigned long long* maskP = (unsigned long long*)(ws + 1150976);  // 32768 B
  float*              hbuf  = (float*)             (ws + 1183744);  // 1048576 B
  float*              obuf  = (float*)             (ws + 2232320);  // 262144 B

  const int SMEM_BYTES = 93696;
  hipFuncSetAttribute((const void*)lstm_kernel,
                      hipFuncAttributeMaxDynamicSharedMemorySize, SMEM_BYTES);

  hipMemsetAsync(sc, 0, 8, stream);
  scale_kernel <<<64, 256, 0, stream>>>(rec, kern, sc);
  prep_kernel  <<<1024, 256, 0, stream>>>(inp, kern, rec, sc, rq, kq, tokB, maskP);
  lstm_kernel  <<<64, 1024, SMEM_BYTES, stream>>>(emb, bias, rq, kq, tokB, maskP, sc, hbuf);
  dense_kernel <<<256, 256, 0, stream>>>(hbuf, dw, db, obuf);
  logits_kernel<<<dim3(391, 4), 256, 0, stream>>>(obuf, emb, dst);
  (void)in_sizes; (void)n_in; (void)out_size; (void)ws_size;
}